// Round 1
// baseline (45.529 us; speedup 1.0000x reference)
//
#include <hip/hip_runtime.h>
#include <float.h>

// Problem constants (from reference)
#define NB 5                  // N_BANDS
#define BB 256                // B
#define LL 800                // L
#define TT (NB * LL)          // 4000 values per batch row
#define NN (TT - (NB - 1) - 1) // 3995 output diffs per row

constexpr int SORT_N = 4096;   // next pow2 >= TT
constexpr int BLOCK = 1024;    // 16 waves

__global__ __launch_bounds__(BLOCK)
void sort_diff_kernel(const float* __restrict__ in,
                      const int* __restrict__ ntotal,
                      float* __restrict__ out)
{
    __shared__ float s[SORT_N];
    const int b   = blockIdx.x;
    const int tid = threadIdx.x;

    // Load this batch's 4000 values. concat[b, k*L + l] = in[k*B*L + b*L + l].
    // Order is irrelevant (we sort), but this indexing is mostly coalesced.
    #pragma unroll
    for (int t = 0; t < SORT_N / BLOCK; ++t) {
        int j = tid + t * BLOCK;
        if (j < TT) {
            int band = j / LL;
            int l    = j - band * LL;
            s[j] = in[(band * BB + b) * LL + l];
        } else {
            s[j] = FLT_MAX;    // pad sorts last (all inputs in [0,1000))
        }
    }
    __syncthreads();

    // Bitonic sort of SORT_N elements in LDS.
    for (int k = 2; k <= SORT_N; k <<= 1) {
        for (int j = k >> 1; j > 0; j >>= 1) {
            #pragma unroll
            for (int t = 0; t < SORT_N / BLOCK; ++t) {
                int i   = tid + t * BLOCK;
                int ixj = i ^ j;
                if (ixj > i) {
                    float a = s[i];
                    float c = s[ixj];
                    bool dir = ((i & k) == 0);   // ascending block?
                    if ((a > c) == dir) {        // swap needed
                        s[i]   = c;
                        s[ixj] = a;
                    }
                }
            }
            __syncthreads();
        }
    }

    // diffs: out[b,i] = sorted[i+5] - sorted[i+4], masked by i < N_total[b].
    const int nt = ntotal[b];
    for (int i = tid; i < NN; i += BLOCK) {
        float d = s[i + NB] - s[i + NB - 1];
        out[b * NN + i] = (i < nt) ? d : 0.0f;
    }
}

extern "C" void kernel_launch(void* const* d_in, const int* in_sizes, int n_in,
                              void* d_out, int out_size, void* d_ws, size_t ws_size,
                              hipStream_t stream) {
    const float* in = (const float*)d_in[0];   // (5, 256, 800) fp32
    const int*   nt = (const int*)d_in[1];     // (256,) int32
    float*       out = (float*)d_out;          // (256, 3995) fp32
    (void)in_sizes; (void)n_in; (void)out_size; (void)d_ws; (void)ws_size;
    sort_diff_kernel<<<BB, BLOCK, 0, stream>>>(in, nt, out);
}

// Round 2
// 18.406 us; speedup vs baseline: 2.4736x; 2.4736x over previous
//
#include <hip/hip_runtime.h>
#include <float.h>

// Problem constants (from reference)
#define NB 5                    // N_BANDS
#define BB 256                  // B
#define LL 800                  // L
#define TT (NB * LL)            // 4000 values per batch row
#define NN (TT - (NB - 1) - 1)  // 3995 output diffs per row

constexpr int BLOCK = 1024;     // 16 waves
constexpr int NBUK  = 1024;     // one bucket per thread; lambda ~= 3.9

__global__ __launch_bounds__(BLOCK)
void bucket_sort_diff(const float* __restrict__ in,
                      const int* __restrict__ ntotal,
                      float* __restrict__ out)
{
    __shared__ float vals[TT];      // 16000 B, sorted result
    __shared__ int   cnt[NBUK];     // histogram, then scatter cursor, then bucket end
    __shared__ int   start[NBUK];   // exclusive prefix (bucket begin)
    __shared__ int   wsum[16];      // per-wave totals for the scan
    __shared__ int   woff[16];      // per-wave exclusive offsets

    const int b    = blockIdx.x;
    const int tid  = threadIdx.x;
    const int lane = tid & 63;
    const int wid  = tid >> 6;

    cnt[tid] = 0;
    __syncthreads();

    // ---- Phase 1: load up to 4 values into registers, LDS-atomic histogram
    float v[4];
    int   bk[4];
    const float scale = (float)NBUK / 1000.0f;   // values uniform in [0,1000)
    #pragma unroll
    for (int k = 0; k < 4; ++k) {
        int j = tid + k * BLOCK;
        if (j < TT) {
            int band = j / LL;
            int l    = j - band * LL;
            float x  = in[(band * BB + b) * LL + l];
            int bb   = (int)(x * scale);
            bb = bb < 0 ? 0 : (bb > NBUK - 1 ? NBUK - 1 : bb);  // monotonic, clamped
            v[k]  = x;
            bk[k] = bb;
            atomicAdd(&cnt[bb], 1);
        } else {
            bk[k] = -1; v[k] = 0.0f;
        }
    }
    __syncthreads();

    // ---- Phase 2: exclusive prefix sum over 1024 bucket counts (shuffle scan)
    int c   = cnt[tid];
    int inc = c;                       // inclusive within-wave scan
    #pragma unroll
    for (int d = 1; d < 64; d <<= 1) {
        int t = __shfl_up(inc, d);
        if (lane >= d) inc += t;
    }
    if (lane == 63) wsum[wid] = inc;
    __syncthreads();
    if (tid < 64) {                    // scan the 16 wave totals in wave 0
        int w  = (tid < 16) ? wsum[tid] : 0;
        int wi = w;
        #pragma unroll
        for (int d = 1; d < 16; d <<= 1) {
            int t = __shfl_up(wi, d);
            if (lane >= d) wi += t;
        }
        if (tid < 16) woff[tid] = wi - w;   // exclusive wave offset
    }
    __syncthreads();
    int excl = (inc - c) + woff[wid];
    start[tid] = excl;
    cnt[tid]   = excl;                 // becomes the scatter cursor
    __syncthreads();

    // ---- Phase 3: scatter into bucket-ordered positions
    #pragma unroll
    for (int k = 0; k < 4; ++k) {
        if (bk[k] >= 0) {
            int pos = atomicAdd(&cnt[bk[k]], 1);
            vals[pos] = v[k];
        }
    }
    __syncthreads();

    // ---- Phase 4: per-thread insertion sort of its (tiny) bucket
    {
        int lo = start[tid];
        int hi = cnt[tid];             // cursor end == bucket end
        for (int i = lo + 1; i < hi; ++i) {
            float key = vals[i];
            int j = i - 1;
            while (j >= lo && vals[j] > key) {
                vals[j + 1] = vals[j];
                --j;
            }
            vals[j + 1] = key;
        }
    }
    __syncthreads();

    // ---- Phase 5: adjacent diffs of sorted[4:], masked, coalesced store
    const int nt = ntotal[b];
    for (int i = tid; i < NN; i += BLOCK) {
        float d = vals[i + NB] - vals[i + NB - 1];
        out[b * NN + i] = (i < nt) ? d : 0.0f;
    }
}

extern "C" void kernel_launch(void* const* d_in, const int* in_sizes, int n_in,
                              void* d_out, int out_size, void* d_ws, size_t ws_size,
                              hipStream_t stream) {
    const float* in  = (const float*)d_in[0];   // (5, 256, 800) fp32
    const int*   nt  = (const int*)d_in[1];     // (256,) int32
    float*       out = (float*)d_out;           // (256, 3995) fp32
    (void)in_sizes; (void)n_in; (void)out_size; (void)d_ws; (void)ws_size;
    bucket_sort_diff<<<BB, BLOCK, 0, stream>>>(in, nt, out);
}

// Round 3
// 12.404 us; speedup vs baseline: 3.6706x; 1.4839x over previous
//
#include <hip/hip_runtime.h>
#include <float.h>

// Problem constants (from reference)
#define NB 5                    // N_BANDS
#define BB 256                  // B
#define LL 800                  // L
#define TT (NB * LL)            // 4000 values per batch row
#define NN (TT - (NB - 1) - 1)  // 3995 output diffs per row

constexpr int BLOCK = 1024;     // 16 waves
constexpr int NBUK  = 4096;     // lambda ~= 0.98, max bucket ~7
constexpr int EPT   = 4;        // elements per thread (4*1024 >= 4000)
constexpr int BPT   = NBUK / BLOCK;  // buckets per thread in the scan

__global__ __launch_bounds__(BLOCK)
void bucket_rank_diff(const float* __restrict__ in,
                      const int* __restrict__ ntotal,
                      float* __restrict__ out)
{
    __shared__ float scat[TT];      // bucket-grouped (unsorted within bucket)
    __shared__ float srt[TT];       // fully sorted
    __shared__ int   cnt[NBUK];     // histogram -> scatter cursor -> bucket end
    __shared__ int   bstart[NBUK];  // bucket begin
    __shared__ int   wsum[16];
    __shared__ int   woff[16];

    const int b    = blockIdx.x;
    const int tid  = threadIdx.x;
    const int lane = tid & 63;
    const int wid  = tid >> 6;

    #pragma unroll
    for (int k = 0; k < BPT; ++k) cnt[tid + k * BLOCK] = 0;
    __syncthreads();

    // ---- Phase 1: load EPT values into registers, LDS-atomic histogram
    float v[EPT];
    int   bk[EPT];
    int   pp[EPT];
    const float scale = (float)NBUK / 1000.0f;   // values uniform in [0,1000)
    #pragma unroll
    for (int k = 0; k < EPT; ++k) {
        int j = tid + k * BLOCK;
        if (j < TT) {
            int band = j / LL;
            int l    = j - band * LL;
            float x  = in[(band * BB + b) * LL + l];
            int bb   = (int)(x * scale);
            bb = bb < 0 ? 0 : (bb > NBUK - 1 ? NBUK - 1 : bb);  // monotone, clamped
            v[k]  = x;
            bk[k] = bb;
            atomicAdd(&cnt[bb], 1);
        } else {
            bk[k] = -1; v[k] = 0.0f;
        }
    }
    __syncthreads();

    // ---- Phase 2: exclusive prefix sum over NBUK counts.
    // Thread t owns contiguous buckets [BPT*t, BPT*t+BPT).
    int c[BPT];
    int s = 0;
    #pragma unroll
    for (int k = 0; k < BPT; ++k) { c[k] = cnt[BPT * tid + k]; s += c[k]; }
    int inc = s;                       // inclusive within-wave scan of thread sums
    #pragma unroll
    for (int d = 1; d < 64; d <<= 1) {
        int t = __shfl_up(inc, d);
        if (lane >= d) inc += t;
    }
    if (lane == 63) wsum[wid] = inc;
    __syncthreads();
    if (tid < 64) {                    // scan the 16 wave totals in wave 0
        int w  = (tid < 16) ? wsum[tid] : 0;
        int wi = w;
        #pragma unroll
        for (int d = 1; d < 16; d <<= 1) {
            int t = __shfl_up(wi, d);
            if (lane >= d) wi += t;
        }
        if (tid < 16) woff[tid] = wi - w;
    }
    __syncthreads();
    int run = (inc - s) + woff[wid];   // exclusive offset for this thread's first bucket
    #pragma unroll
    for (int k = 0; k < BPT; ++k) {
        bstart[BPT * tid + k] = run;
        cnt[BPT * tid + k]    = run;   // becomes scatter cursor
        run += c[k];
    }
    __syncthreads();

    // ---- Phase 3: scatter into bucket-grouped positions (unordered in-bucket)
    #pragma unroll
    for (int k = 0; k < EPT; ++k) {
        if (bk[k] >= 0) {
            pp[k] = atomicAdd(&cnt[bk[k]], 1);
            scat[pp[k]] = v[k];
        }
    }
    __syncthreads();

    // ---- Phase 4: parallel rank-count within bucket, write sorted array.
    // rank = #{ j in bucket : s[j] < v  ||  (s[j]==v && j < myPos) }  (unique)
    #pragma unroll
    for (int k = 0; k < EPT; ++k) {
        if (bk[k] >= 0) {
            int lo = bstart[bk[k]];
            int hi = cnt[bk[k]];       // cursor end == bucket end
            float x = v[k];
            int   p = pp[k];
            int   r = lo;
            for (int j = lo; j < hi; ++j) {
                float w = scat[j];
                if (w < x || (w == x && j < p)) ++r;
            }
            srt[r] = x;
        }
    }
    __syncthreads();

    // ---- Phase 5: adjacent diffs of sorted[4:], masked, coalesced store
    const int nt = ntotal[b];
    #pragma unroll
    for (int k = 0; k < EPT; ++k) {
        int i = tid + k * BLOCK;
        if (i < NN) {
            float d = srt[i + NB] - srt[i + NB - 1];
            out[b * NN + i] = (i < nt) ? d : 0.0f;
        }
    }
}

extern "C" void kernel_launch(void* const* d_in, const int* in_sizes, int n_in,
                              void* d_out, int out_size, void* d_ws, size_t ws_size,
                              hipStream_t stream) {
    const float* in  = (const float*)d_in[0];   // (5, 256, 800) fp32
    const int*   nt  = (const int*)d_in[1];     // (256,) int32
    float*       out = (float*)d_out;           // (256, 3995) fp32
    (void)in_sizes; (void)n_in; (void)out_size; (void)d_ws; (void)ws_size;
    bucket_rank_diff<<<BB, BLOCK, 0, stream>>>(in, nt, out);
}